// Round 18
// baseline (61.406 us; speedup 1.0000x reference)
//
#include <hip/hip_runtime.h>
#include <hip/hip_bf16.h>
#include <hip/hip_fp8.h>
#include <stdint.h>

// VQ: z (32,256,32,32) f32 NCHW, codebook (1024,256) f32
// out: z_q (8388608 f32 NCHW) + commit_loss (1 f32 at out[8388608])
//
// R18 = R17 with k1 reshaped for arithmetic intensity + block TLP:
// eighth-codebook blocks (128 codes, 32KB LDS) x 64 pos/wave (pf=4).
// 1024 blocks x 256 thr -> 4 blocks/CU, 16 waves/CU; each ds_read_b128
// feeds 4 MFMAs (was 2) -> per-CU ds_read floor halves. Stage-once,
// barrier-free main loop (proven R10). penc = 8 eighths (1MB); k2 does
// 8-way merge. k0 mapping identical with eighth granularity.
// No-go ledger (measured): per-block fence+atomic +17us (R15); in-loop
// stage barriers +10-20us (R12/R13); per-block cb re-conversion +20us
// (R11); <16 waves/CU +15us (R13). absmax 1.953e-3 (fp8 argmin, proven).

#define WS_CN    0                 // 1024 f32 (4KB)
#define WS_CB    4096              // 256 KB fp8 frags
#define WS_PENC  266240            // 8*32768 f32 = 1 MB
#define WS_PART2 1314816           // 128 f32 (z^2 partials)
#define WS_PART  1315328           // 512 f32 (minS partials)

typedef float f32x4 __attribute__((ext_vector_type(4)));
typedef long  i64;
typedef long  l64x2 __attribute__((ext_vector_type(2)));

template <bool HI>
static __device__ __forceinline__ unsigned pk2(float a, float b, unsigned old) {
#if __has_builtin(__builtin_amdgcn_cvt_pk_fp8_f32)
    return (unsigned)__builtin_amdgcn_cvt_pk_fp8_f32(a, b, (int)old, HI);
#else
    __hip_fp8_e4m3 qa(a), qb(b);
    unsigned w = (unsigned)qa.__x | ((unsigned)qb.__x << 8);
    return HI ? ((old & 0x0000FFFFu) | (w << 16)) : ((old & 0xFFFF0000u) | w);
#endif
}

// ---------------- K0: cnorm*256 + (-512*codebook) fp8 fragment-ordered ----------------
// frag unit (16B) = [e8][chunk8][kp4][lane64]; lane = g4*16 + r16 holds
// A[row=r16][k = ks*32 + g4*8 + j]; bytes (ks&1)*8 + j.
// 128 blocks x 512 thr: wave w of block b preps code b*8+w.
__global__ __launch_bounds__(512) void k0_prep(const float* __restrict__ cb,
                                               float* __restrict__ cn256,
                                               unsigned char* __restrict__ cbf8) {
    const int w = threadIdx.x >> 6;
    const int l = threadIdx.x & 63;
    const int code = blockIdx.x * 8 + w;
    const float4 v = ((const float4*)cb)[code * 64 + l];   // k = 4l..4l+3
    float nrm = v.x * v.x + v.y * v.y + v.z * v.z + v.w * v.w;
    #pragma unroll
    for (int off = 1; off < 64; off <<= 1) nrm += __shfl_xor(nrm, off);
    if (l == 0) cn256[code] = 256.f * nrm;
    unsigned u = pk2<false>(-512.f * v.x, -512.f * v.y, 0u);
    u = pk2<true>(-512.f * v.z, -512.f * v.w, u);
    const int e = code >> 7, chunk = (code >> 4) & 7, r16 = code & 15;
    const int kp = l >> 4, g4 = (l >> 1) & 3;
    const int lane = g4 * 16 + r16;
    const int byteoff = e * 32768 + ((chunk * 4 + kp) * 64 + lane) * 16
                      + ((l >> 3) & 1) * 8 + (l & 1) * 4;
    *(unsigned*)(cbf8 + byteoff) = u;
}

// ---------------- K1: per-eighth distances + encoded argmin ----------------
__global__ __launch_bounds__(256) void k1_main(const float* __restrict__ z,
                                               const unsigned char* __restrict__ cbf8,
                                               const float* __restrict__ cn256,
                                               float* __restrict__ penc,
                                               float* __restrict__ part2) {
    __shared__ __align__(16) unsigned char lds[32768];
    __shared__ float redz[4];
    const int t = threadIdx.x, w = t >> 6, l = t & 63;
    const int col = l & 15, g4 = l >> 4, gc4 = g4 * 4;
    const int b = blockIdx.x, e = b >> 7, grp = b & 127;   // e-major: co-XCD per grp
    const int img = grp >> 2, hw0 = (grp & 3) << 8;        // 256 pos per group

    // stage eighth codebook (32 KB) -> LDS, stage-ONCE
    {
        const unsigned char* src = cbf8 + e * 32768;
        #pragma unroll
        for (int i = 0; i < 8; ++i) {
            const int off = i * 4096 + w * 1024;
            __builtin_amdgcn_global_load_lds(
                (const __attribute__((address_space(1))) unsigned*)(src + off + l * 16),
                (__attribute__((address_space(3))) unsigned*)(lds + off), 16, 0, 0);
        }
    }

    // z -> fp8 B-frags (64 pos per wave, pf=4) + z^2 (f32)
    const float* zp = z + img * 262144 + hw0 + w * 64;
    float z2 = 0.f;
    i64 zf[4][8];
    #pragma unroll
    for (int pf = 0; pf < 4; ++pf) {
        const int p = pf * 16 + col;
        #pragma unroll
        for (int ks = 0; ks < 8; ++ks) {
            const float* s0 = zp + (ks * 32 + g4 * 8) * 1024 + p;
            float v0 = s0[0], v1 = s0[1024], v2 = s0[2048], v3 = s0[3072];
            float v4 = s0[4096], v5 = s0[5120], v6 = s0[6144], v7 = s0[7168];
            z2 += v0*v0 + v1*v1 + v2*v2 + v3*v3 + v4*v4 + v5*v5 + v6*v6 + v7*v7;
            unsigned lo = pk2<false>(v0, v1, 0u); lo = pk2<true>(v2, v3, lo);
            unsigned hi = pk2<false>(v4, v5, 0u); hi = pk2<true>(v6, v7, hi);
            zf[pf][ks] = (i64)(((unsigned long)hi << 32) | (unsigned long)lo);
        }
    }
    __syncthreads();   // staging complete; main loop barrier-free

    float menc0 = __builtin_bit_cast(float, 0x7F7FFC00u);
    float menc1 = __builtin_bit_cast(float, 0x7F7FFC00u);
    float menc2 = __builtin_bit_cast(float, 0x7F7FFC00u);
    float menc3 = __builtin_bit_cast(float, 0x7F7FFC00u);

    #pragma unroll 1
    for (int c = 0; c < 8; ++c) {          // 8 chunks x 16 codes
        i64 A[8];
        #pragma unroll
        for (int kp = 0; kp < 4; ++kp) {
            l64x2 u = *(const l64x2*)(lds + ((c * 4 + kp) * 64 + l) * 16);
            A[2 * kp] = u.x; A[2 * kp + 1] = u.y;
        }
        f32x4 a0 = {0.f,0.f,0.f,0.f}, a1 = {0.f,0.f,0.f,0.f};
        f32x4 a2 = {0.f,0.f,0.f,0.f}, a3 = {0.f,0.f,0.f,0.f};
        #pragma unroll
        for (int ks = 0; ks < 8; ++ks) {   // 4 independent chains per ds_read
            a0 = __builtin_amdgcn_mfma_f32_16x16x32_fp8_fp8(A[ks], zf[0][ks], a0, 0, 0, 0);
            a1 = __builtin_amdgcn_mfma_f32_16x16x32_fp8_fp8(A[ks], zf[1][ks], a1, 0, 0, 0);
            a2 = __builtin_amdgcn_mfma_f32_16x16x32_fp8_fp8(A[ks], zf[2][ks], a2, 0, 0, 0);
            a3 = __builtin_amdgcn_mfma_f32_16x16x32_fp8_fp8(A[ks], zf[3][ks], a3, 0, 0, 0);
        }
        const f32x4 cn = *(const f32x4*)(cn256 + e * 128 + c * 16 + gc4);
        #pragma unroll
        for (int r = 0; r < 4; ++r) {
            const unsigned code0 = (unsigned)(e * 128 + c * 16 + gc4 + r);
            float s; unsigned u;
            s = a0[r] + cn[r];
            u = (__builtin_bit_cast(unsigned, s) & 0xFFFFFC00u) | code0;
            menc0 = fminf(menc0, __builtin_bit_cast(float, u));
            s = a1[r] + cn[r];
            u = (__builtin_bit_cast(unsigned, s) & 0xFFFFFC00u) | code0;
            menc1 = fminf(menc1, __builtin_bit_cast(float, u));
            s = a2[r] + cn[r];
            u = (__builtin_bit_cast(unsigned, s) & 0xFFFFFC00u) | code0;
            menc2 = fminf(menc2, __builtin_bit_cast(float, u));
            s = a3[r] + cn[r];
            u = (__builtin_bit_cast(unsigned, s) & 0xFFFFFC00u) | code0;
            menc3 = fminf(menc3, __builtin_bit_cast(float, u));
        }
    }

    // merge across the 4 g-groups sharing each pos column
    menc0 = fminf(menc0, __shfl_xor(menc0, 16));
    menc0 = fminf(menc0, __shfl_xor(menc0, 32));
    menc1 = fminf(menc1, __shfl_xor(menc1, 16));
    menc1 = fminf(menc1, __shfl_xor(menc1, 32));
    menc2 = fminf(menc2, __shfl_xor(menc2, 16));
    menc2 = fminf(menc2, __shfl_xor(menc2, 32));
    menc3 = fminf(menc3, __shfl_xor(menc3, 16));
    menc3 = fminf(menc3, __shfl_xor(menc3, 32));
    if (l < 16) {
        const int pbase = e * 32768 + grp * 256 + w * 64;
        penc[pbase + l]      = menc0;
        penc[pbase + 16 + l] = menc1;
        penc[pbase + 32 + l] = menc2;
        penc[pbase + 48 + l] = menc3;
    }

    // z^2 partial (identical across eighths -> only e==0 contributes)
    #pragma unroll
    for (int off = 1; off < 64; off <<= 1) z2 += __shfl_xor(z2, off);
    if (l == 0) redz[w] = z2;
    __syncthreads();
    if (t == 0 && e == 0) part2[grp] = redz[0] + redz[1] + redz[2] + redz[3];
}

// ---------------- K2: 8-way merge + z_q gather/transpose + vectorized NCHW write ----------------
__global__ __launch_bounds__(256) void k2_out(const float* __restrict__ cbf,
                                              const float* __restrict__ penc,
                                              float* __restrict__ out,
                                              float* __restrict__ part) {
    __shared__ __align__(16) float zqbuf[32 * 260];
    __shared__ unsigned idxl[64];
    const int t = threadIdx.x, b = blockIdx.x;
    const int pos0 = b * 64, img = pos0 >> 10, hw0 = pos0 & 1023;

    if (t < 64) {
        const int pos = pos0 + t;
        const float e01 = fminf(penc[pos],          penc[32768 + pos]);
        const float e23 = fminf(penc[65536 + pos],  penc[98304 + pos]);
        const float e45 = fminf(penc[131072 + pos], penc[163840 + pos]);
        const float e67 = fminf(penc[196608 + pos], penc[229376 + pos]);
        const float e = fminf(fminf(e01, e23), fminf(e45, e67));
        const unsigned eu = __builtin_bit_cast(unsigned, e);
        idxl[t] = eu & 0x3FFu;
        float myS = __builtin_bit_cast(float, eu & 0xFFFFFC00u);
        #pragma unroll
        for (int off = 1; off < 64; off <<= 1) myS += __shfl_xor(myS, off);
        if (t == 0) part[b] = myS * (1.f / 256.f);
    }

    const float4* cb4 = (const float4*)cbf;
    const int pq = t & 7;          // pos-quad 0..7 (p = pq*4 + 0..3)
    const int cg = t >> 3;         // 0..31 (ch = i*32 + cg)
    for (int h = 0; h < 2; ++h) {
        __syncthreads();
        #pragma unroll
        for (int i = 0; i < 8; ++i) {
            const int flat = i * 256 + t;        // [0,2048)
            const int p = flat >> 6;             // row 0..31
            const int qq = flat & 63;            // float4 index
            const unsigned code = idxl[h * 32 + p];
            *(float4*)&zqbuf[p * 260 + qq * 4] = cb4[code * 64 + qq];
        }
        __syncthreads();
        float* ob = out + img * 262144 + hw0 + h * 32 + pq * 4;
        #pragma unroll
        for (int i = 0; i < 8; ++i) {
            const int ch = i * 32 + cg;
            float4 v;
            v.x = zqbuf[(pq * 4 + 0) * 260 + ch];
            v.y = zqbuf[(pq * 4 + 1) * 260 + ch];
            v.z = zqbuf[(pq * 4 + 2) * 260 + ch];
            v.w = zqbuf[(pq * 4 + 3) * 260 + ch];
            *(float4*)(ob + ch * 1024) = v;
        }
    }
}

// ---------------- K3: deterministic final loss reduce ----------------
__global__ __launch_bounds__(256) void k3_red(const float* __restrict__ part2,
                                              const float* __restrict__ part,
                                              float* __restrict__ out) {
    __shared__ float red[256];
    const int t = threadIdx.x;
    float v = part[t] + part[t + 256];
    if (t < 128) v += part2[t];
    red[t] = v;
    __syncthreads();
    #pragma unroll
    for (int off = 128; off > 0; off >>= 1) {
        if (t < off) red[t] += red[t + off];
        __syncthreads();
    }
    if (t == 0) out[8388608] = 1.25f * red[0] / 8388608.f;
}

extern "C" void kernel_launch(void* const* d_in, const int* in_sizes, int n_in,
                              void* d_out, int out_size, void* d_ws, size_t ws_size,
                              hipStream_t stream) {
    const float* z  = (const float*)d_in[0];
    const float* cb = (const float*)d_in[1];
    float* out = (float*)d_out;
    unsigned char* ws = (unsigned char*)d_ws;
    float* cn256 = (float*)(ws + WS_CN);
    unsigned char* cbf8 = ws + WS_CB;
    float* penc  = (float*)(ws + WS_PENC);
    float* part2 = (float*)(ws + WS_PART2);
    float* part  = (float*)(ws + WS_PART);

    hipLaunchKernelGGL(k0_prep, dim3(128), dim3(512), 0, stream, cb, cn256, cbf8);
    hipLaunchKernelGGL(k1_main, dim3(1024), dim3(256), 0, stream, z, cbf8, cn256, penc, part2);
    hipLaunchKernelGGL(k2_out,  dim3(512), dim3(256), 0, stream, cb, penc, out, part);
    hipLaunchKernelGGL(k3_red,  dim3(1), dim3(256), 0, stream, part2, part, out);
}

// Round 19
// 44.640 us; speedup vs baseline: 1.3756x; 1.3756x over previous
//
#include <hip/hip_runtime.h>
#include <hip/hip_bf16.h>
#include <hip/hip_fp8.h>
#include <stdint.h>

// VQ: z (32,256,32,32) f32 NCHW, codebook (1024,256) f32
// out: z_q (8388608 f32 NCHW) + commit_loss (1 f32 at out[8388608])
//
// R19 = R17 byte-identical (revert of R18's regression; R18: zf[4] reshape
// -> 188 VGPR -> 8 waves/CU -> 61.4us, violating the <16-waves rule).
// This structure is the REPLICATED best: 45.1/45.3/45.4us (R17/R16/R10).
// Structure: k0 prep (fp8 e4m3 x-512 fragment-ordered codebook + 256*norms)
// -> k1 quarter-codebook LDS-resident, stage-once, barrier-free MFMA loop,
// encoded argmin (S&~0x3FF)|code -> k2 4-way merge + gather/transpose +
// vectorized NCHW write -> k3 deterministic loss reduce.
// Measured no-go ledger: fence+atomic rendezvous +17us (R15); in-loop
// stage barriers +10-20us (R12/R13); per-block cb re-conversion +20us
// (R11); <16 waves/CU +15us (R13/R18); 32x32 MFMA +14us (R14);
// neutral: k2 store vectorization (R16), k0 consolidation (R17).
// absmax 1.953e-3 (fp8 argmin perturbation, proven R9..R18).

#define WS_CN    0                 // 1024 f32 (4KB)
#define WS_CB    4096              // 256 KB fp8 frags
#define WS_PENC  266240            // 4*32768 f32 = 512 KB
#define WS_PART2 790528            // 128 f32 (z^2 partials)
#define WS_PART  791040            // 512 f32 (minS partials)

typedef float f32x4 __attribute__((ext_vector_type(4)));
typedef long  i64;
typedef long  l64x2 __attribute__((ext_vector_type(2)));

template <bool HI>
static __device__ __forceinline__ unsigned pk2(float a, float b, unsigned old) {
#if __has_builtin(__builtin_amdgcn_cvt_pk_fp8_f32)
    return (unsigned)__builtin_amdgcn_cvt_pk_fp8_f32(a, b, (int)old, HI);
#else
    __hip_fp8_e4m3 qa(a), qb(b);
    unsigned w = (unsigned)qa.__x | ((unsigned)qb.__x << 8);
    return HI ? ((old & 0x0000FFFFu) | (w << 16)) : ((old & 0xFFFF0000u) | w);
#endif
}

// ---------------- K0: cnorm*256 + (-512*codebook) fp8 fragment-ordered ----------------
// frag unit (16B) = [q][chunk16][kp4][lane64]; lane = g4*16 + r16 holds
// A[row=r16][k = ks*32 + g4*8 + j]; bytes (ks&1)*8 + j, ks = 2kp, 2kp+1.
// 128 blocks x 512 thr: wave w of block b preps code b*8+w.
__global__ __launch_bounds__(512) void k0_prep(const float* __restrict__ cb,
                                               float* __restrict__ cn256,
                                               unsigned char* __restrict__ cbf8) {
    const int w = threadIdx.x >> 6;
    const int l = threadIdx.x & 63;
    const int code = blockIdx.x * 8 + w;
    const float4 v = ((const float4*)cb)[code * 64 + l];   // k = 4l..4l+3
    float nrm = v.x * v.x + v.y * v.y + v.z * v.z + v.w * v.w;
    #pragma unroll
    for (int off = 1; off < 64; off <<= 1) nrm += __shfl_xor(nrm, off);
    if (l == 0) cn256[code] = 256.f * nrm;
    unsigned u = pk2<false>(-512.f * v.x, -512.f * v.y, 0u);
    u = pk2<true>(-512.f * v.z, -512.f * v.w, u);
    const int q = code >> 8, chunk = (code >> 4) & 15, r16 = code & 15;
    const int ks = l >> 3, kp = l >> 4, g4 = (l >> 1) & 3;
    const int lane = g4 * 16 + r16;
    const int byteoff = q * 65536 + ((chunk * 4 + kp) * 64 + lane) * 16
                      + (ks & 1) * 8 + (l & 1) * 4;
    *(unsigned*)(cbf8 + byteoff) = u;
}

// ---------------- K1: per-quarter distances + encoded argmin (R10 verbatim) ----------------
__global__ __launch_bounds__(512) void k1_main(const float* __restrict__ z,
                                               const unsigned char* __restrict__ cbf8,
                                               const float* __restrict__ cn256,
                                               float* __restrict__ penc,
                                               float* __restrict__ part2) {
    __shared__ __align__(16) unsigned char lds[65536];
    const int t = threadIdx.x, w = t >> 6, l = t & 63;
    const int col = l & 15, g4 = l >> 4, gc4 = g4 * 4;
    const int b = blockIdx.x, q = b >> 7, grp = b & 127;   // q-major: co-XCD per grp
    const int img = grp >> 2, hw0 = (grp & 3) << 8;        // 256 pos per group

    // stage quarter codebook (64 KB) -> LDS, linear, global_load_lds x16B
    {
        const unsigned char* src = cbf8 + q * 65536;
        #pragma unroll
        for (int i = 0; i < 8; ++i) {
            const int off = i * 8192 + w * 1024;
            __builtin_amdgcn_global_load_lds(
                (const __attribute__((address_space(1))) unsigned*)(src + off + l * 16),
                (__attribute__((address_space(3))) unsigned*)(lds + off), 16, 0, 0);
        }
    }

    // z -> fp8 B-frags (32 pos per wave) + z^2 (f32)
    const float* zp = z + img * 262144 + hw0 + w * 32;
    float z2 = 0.f;
    i64 zf[2][8];
    #pragma unroll
    for (int pf = 0; pf < 2; ++pf) {
        const int p = pf * 16 + col;
        #pragma unroll
        for (int ks = 0; ks < 8; ++ks) {
            const float* s0 = zp + (ks * 32 + g4 * 8) * 1024 + p;
            float v0 = s0[0], v1 = s0[1024], v2 = s0[2048], v3 = s0[3072];
            float v4 = s0[4096], v5 = s0[5120], v6 = s0[6144], v7 = s0[7168];
            z2 += v0*v0 + v1*v1 + v2*v2 + v3*v3 + v4*v4 + v5*v5 + v6*v6 + v7*v7;
            unsigned lo = pk2<false>(v0, v1, 0u); lo = pk2<true>(v2, v3, lo);
            unsigned hi = pk2<false>(v4, v5, 0u); hi = pk2<true>(v6, v7, hi);
            zf[pf][ks] = (i64)(((unsigned long)hi << 32) | (unsigned long)lo);
        }
    }
    __syncthreads();   // staging (and z loads) complete

    float menc0 = __builtin_bit_cast(float, 0x7F7FFC00u);
    float menc1 = __builtin_bit_cast(float, 0x7F7FFC00u);

    i64 A0[8], A1[8];
#define LDA(DST, c) do {                                                         \
    _Pragma("unroll") for (int kp = 0; kp < 4; ++kp) {                           \
        l64x2 u = *(const l64x2*)(lds + (((c) * 4 + kp) * 64 + l) * 16);         \
        DST[2 * kp] = u.x; DST[2 * kp + 1] = u.y;                                \
    }                                                                            \
} while (0)
#define BODY(CUR, NXT, c) do {                                                   \
    if ((c) + 1 < 16) LDA(NXT, (c) + 1);                                         \
    f32x4 a0 = {0.f,0.f,0.f,0.f}, a1 = {0.f,0.f,0.f,0.f};                        \
    _Pragma("unroll") for (int ks = 0; ks < 8; ++ks) {                           \
        a0 = __builtin_amdgcn_mfma_f32_16x16x32_fp8_fp8(CUR[ks], zf[0][ks], a0, 0, 0, 0); \
        a1 = __builtin_amdgcn_mfma_f32_16x16x32_fp8_fp8(CUR[ks], zf[1][ks], a1, 0, 0, 0); \
    }                                                                            \
    {                                                                            \
        const f32x4 cn = *(const f32x4*)(cn256 + q * 256 + (c) * 16 + gc4);      \
        _Pragma("unroll") for (int r = 0; r < 4; ++r) {                          \
            const unsigned code0 = (unsigned)(q * 256 + (c) * 16 + gc4 + r);     \
            float s; unsigned e;                                                 \
            s = a0[r] + cn[r];                                                   \
            e = (__builtin_bit_cast(unsigned, s) & 0xFFFFFC00u) | code0;         \
            menc0 = fminf(menc0, __builtin_bit_cast(float, e));                  \
            s = a1[r] + cn[r];                                                   \
            e = (__builtin_bit_cast(unsigned, s) & 0xFFFFFC00u) | code0;         \
            menc1 = fminf(menc1, __builtin_bit_cast(float, e));                  \
        }                                                                        \
    }                                                                            \
} while (0)

    LDA(A0, 0);
    #pragma unroll 1
    for (int c2 = 0; c2 < 16; c2 += 2) {
        BODY(A0, A1, c2);
        BODY(A1, A0, c2 + 1);
    }
#undef BODY
#undef LDA

    // merge across the 4 g-groups sharing each pos column
    menc0 = fminf(menc0, __shfl_xor(menc0, 16));
    menc0 = fminf(menc0, __shfl_xor(menc0, 32));
    menc1 = fminf(menc1, __shfl_xor(menc1, 16));
    menc1 = fminf(menc1, __shfl_xor(menc1, 32));
    const int posbase = img * 1024 + hw0 + w * 32;
    if (l < 16) {
        penc[q * 32768 + posbase + l]      = menc0;
        penc[q * 32768 + posbase + 16 + l] = menc1;
    }

    // z^2 partial (identical across quarters -> only q==0 contributes)
    #pragma unroll
    for (int off = 1; off < 64; off <<= 1) z2 += __shfl_xor(z2, off);
    __syncthreads();                      // codebook reads done; reuse lds head
    float* red = (float*)lds;
    if (l == 0) red[w] = z2;
    __syncthreads();
    if (t == 0 && q == 0) {
        float s = 0.f;
        #pragma unroll
        for (int i = 0; i < 8; ++i) s += red[i];
        part2[grp] = s;
    }
}

// ---------------- K2: 4-way merge + z_q gather/transpose + vectorized NCHW write ----------------
__global__ __launch_bounds__(256) void k2_out(const float* __restrict__ cbf,
                                              const float* __restrict__ penc,
                                              float* __restrict__ out,
                                              float* __restrict__ part) {
    __shared__ __align__(16) float zqbuf[32 * 260];
    __shared__ unsigned idxl[64];
    const int t = threadIdx.x, b = blockIdx.x;
    const int pos0 = b * 64, img = pos0 >> 10, hw0 = pos0 & 1023;

    if (t < 64) {
        const int pos = pos0 + t;
        const float e = fminf(fminf(penc[pos], penc[32768 + pos]),
                              fminf(penc[65536 + pos], penc[98304 + pos]));
        const unsigned eu = __builtin_bit_cast(unsigned, e);
        idxl[t] = eu & 0x3FFu;
        float myS = __builtin_bit_cast(float, eu & 0xFFFFFC00u);
        #pragma unroll
        for (int off = 1; off < 64; off <<= 1) myS += __shfl_xor(myS, off);
        if (t == 0) part[b] = myS * (1.f / 256.f);
    }

    const float4* cb4 = (const float4*)cbf;
    const int pq = t & 7;          // pos-quad 0..7 (p = pq*4 + 0..3)
    const int cg = t >> 3;         // 0..31 (ch = i*32 + cg)
    for (int h = 0; h < 2; ++h) {
        __syncthreads();
        #pragma unroll
        for (int i = 0; i < 8; ++i) {
            const int flat = i * 256 + t;        // [0,2048)
            const int p = flat >> 6;             // row 0..31
            const int qq = flat & 63;            // float4 index
            const unsigned code = idxl[h * 32 + p];
            *(float4*)&zqbuf[p * 260 + qq * 4] = cb4[code * 64 + qq];
        }
        __syncthreads();
        float* ob = out + img * 262144 + hw0 + h * 32 + pq * 4;
        #pragma unroll
        for (int i = 0; i < 8; ++i) {
            const int ch = i * 32 + cg;
            float4 v;
            v.x = zqbuf[(pq * 4 + 0) * 260 + ch];
            v.y = zqbuf[(pq * 4 + 1) * 260 + ch];
            v.z = zqbuf[(pq * 4 + 2) * 260 + ch];
            v.w = zqbuf[(pq * 4 + 3) * 260 + ch];
            *(float4*)(ob + ch * 1024) = v;
        }
    }
}

// ---------------- K3: deterministic final loss reduce ----------------
__global__ __launch_bounds__(256) void k3_red(const float* __restrict__ part2,
                                              const float* __restrict__ part,
                                              float* __restrict__ out) {
    __shared__ float red[256];
    const int t = threadIdx.x;
    float v = part[t] + part[t + 256];
    if (t < 128) v += part2[t];
    red[t] = v;
    __syncthreads();
    #pragma unroll
    for (int off = 128; off > 0; off >>= 1) {
        if (t < off) red[t] += red[t + off];
        __syncthreads();
    }
    if (t == 0) out[8388608] = 1.25f * red[0] / 8388608.f;
}

extern "C" void kernel_launch(void* const* d_in, const int* in_sizes, int n_in,
                              void* d_out, int out_size, void* d_ws, size_t ws_size,
                              hipStream_t stream) {
    const float* z  = (const float*)d_in[0];
    const float* cb = (const float*)d_in[1];
    float* out = (float*)d_out;
    unsigned char* ws = (unsigned char*)d_ws;
    float* cn256 = (float*)(ws + WS_CN);
    unsigned char* cbf8 = ws + WS_CB;
    float* penc  = (float*)(ws + WS_PENC);
    float* part2 = (float*)(ws + WS_PART2);
    float* part  = (float*)(ws + WS_PART);

    hipLaunchKernelGGL(k0_prep, dim3(128), dim3(512), 0, stream, cb, cn256, cbf8);
    hipLaunchKernelGGL(k1_main, dim3(512), dim3(512), 0, stream, z, cbf8, cn256, penc, part2);
    hipLaunchKernelGGL(k2_out,  dim3(512), dim3(256), 0, stream, cb, penc, out, part);
    hipLaunchKernelGGL(k3_red,  dim3(1), dim3(256), 0, stream, part2, part, out);
}